// Round 5
// baseline (1925.350 us; speedup 1.0000x reference)
//
#include <hip/hip_runtime.h>
#include <hip/hip_bf16.h>

#define NEG_SLOPE 0.2f

typedef __attribute__((ext_vector_type(8))) short bf16x8;
typedef __attribute__((ext_vector_type(4))) float f32x4;

__device__ __forceinline__ unsigned short bf16hi(float v) {
    __hip_bfloat16 h = __float2bfloat16(v);
    return *(unsigned short*)&h;
}
__device__ __forceinline__ float bf16tof(unsigned short u) {
    __hip_bfloat16 h = *(__hip_bfloat16*)&u;
    return __bfloat162float(h);
}

// ---------------------------------------------------------------------------
// CSR build
// ---------------------------------------------------------------------------
__global__ void hist_kernel(const int* __restrict__ dst, int* __restrict__ cnt, int E) {
    int e = blockIdx.x * 256 + threadIdx.x;
    if (e < E) atomicAdd(&cnt[dst[e]], 1);
}

__global__ void scan_s1(const int* __restrict__ cnt, int* __restrict__ excl,
                        int* __restrict__ totals, int N) {
    __shared__ int lds[256];
    int t = threadIdx.x;
    int i = blockIdx.x * 256 + t;
    int v = (i < N) ? cnt[i] : 0;
    lds[t] = v;
    __syncthreads();
    #pragma unroll
    for (int off = 1; off < 256; off <<= 1) {
        int add = (t >= off) ? lds[t - off] : 0;
        __syncthreads();
        lds[t] += add;
        __syncthreads();
    }
    if (i < N) excl[i] = lds[t] - v;
    if (t == 255) totals[blockIdx.x] = lds[255];
}

__global__ void scan_s2(int* __restrict__ totals, int nb) {
    __shared__ int lds[256];
    int t = threadIdx.x;
    int v = (t < nb) ? totals[t] : 0;
    lds[t] = v;
    __syncthreads();
    #pragma unroll
    for (int off = 1; off < 256; off <<= 1) {
        int add = (t >= off) ? lds[t - off] : 0;
        __syncthreads();
        lds[t] += add;
        __syncthreads();
    }
    if (t < nb) totals[t] = lds[t] - v;   // exclusive over block totals
}

__global__ void scan_s3(int* __restrict__ row_ptr, const int* __restrict__ totals,
                        int* __restrict__ cursor, int N, int E) {
    int i = blockIdx.x * 256 + threadIdx.x;
    if (i < N) {
        int v = row_ptr[i] + totals[blockIdx.x];
        row_ptr[i] = v;
        cursor[i] = v;
    }
    if (i == 0) row_ptr[N] = E;
}

__global__ void scatter_kernel(const int* __restrict__ src, const int* __restrict__ dst,
                               int* __restrict__ cursor, int* __restrict__ col_src,
                               int* __restrict__ col_eid, int E) {
    int e = blockIdx.x * 256 + threadIdx.x;
    if (e < E) {
        int d = dst[e];
        int pos = atomicAdd(&cursor[d], 1);
        col_src[pos] = src[e];
        col_eid[pos] = e;
    }
}

// ---------------------------------------------------------------------------
// Pack We (fp32 [32,256]) into MFMA A-fragment order, bf16 hi + lo parts.
// WeP layout: [layer][part][tile][lane][8] shorts; layer stride 16384,
// lo part at +8192. A[m=lane&15][k=(lane>>4)*8+j].
// ---------------------------------------------------------------------------
__global__ void pack_we(const float* __restrict__ We0, const float* __restrict__ We1,
                        unsigned short* __restrict__ WeP) {
    int t = blockIdx.x * 256 + threadIdx.x;
    if (t >= 4096) return;
    int layer = t >> 11;
    int part  = (t >> 10) & 1;
    int tile  = (t >> 6) & 15;
    int lane  = t & 63;
    const float* We = layer ? We1 : We0;
    int ch = tile * 16 + (lane & 15);
    int kb = (lane >> 4) * 8;
    union { unsigned short u[8]; uint4 v; } out;
    #pragma unroll
    for (int j = 0; j < 8; ++j) {
        float w = We[(size_t)(kb + j) * 256 + ch];
        unsigned short hi = bf16hi(w);
        out.u[j] = part ? bf16hi(w - bf16tof(hi)) : hi;
    }
    *(uint4*)(WeP + (size_t)t * 8) = out.v;
}

// ---------------------------------------------------------------------------
// Pack W = [Wl | Wr] (fp32 [K,256] each) into MFMA B-frag order, hi+lo bf16.
// Layout: [part(2)][kt(KT)][ntglob(32)][lane(64)][8] shorts.
// B[n=nt*16+(lane&15)][k=kt*32+(lane>>4)*8+j].
// ---------------------------------------------------------------------------
__global__ void pack_w(const float* __restrict__ Wl, const float* __restrict__ Wr,
                       int KT, unsigned short* __restrict__ out) {
    int t = blockIdx.x * 256 + threadIdx.x;
    int per = KT * 2048;             // KT*32*64
    if (t >= 2 * per) return;
    int part = t / per;
    int rem  = t % per;
    int kt   = rem >> 11;
    int nt   = (rem >> 6) & 31;
    int lane = rem & 63;
    int n  = nt * 16 + (lane & 15);
    int kb = kt * 32 + ((lane >> 4) * 8);
    const float* W = (n < 256) ? (Wl + n) : (Wr + (n - 256));
    union { unsigned short u[8]; uint4 v; } o;
    #pragma unroll
    for (int j = 0; j < 8; ++j) {
        float w = W[(size_t)(kb + j) * 256];
        unsigned short hi = bf16hi(w);
        o.u[j] = part ? bf16hi(w - bf16tof(hi)) : hi;
    }
    *(uint4*)(out + (size_t)t * 8) = o.v;
}

// ---------------------------------------------------------------------------
// Split-bf16 MFMA GEMM: C[M,512] = A[M,K] @ [Wl|Wr] + [bl|br], fp32-accurate
// via 3-term hi/lo split. Block = 128 rows x 128 cols, 4 waves; wave handles
// 2 row-tiles x 8 col-tiles. A staged to LDS as hi/lo bf16 frags per K-step.
// ---------------------------------------------------------------------------
__global__ __launch_bounds__(256) void gemm_split(
    const float* __restrict__ A, int M, int K,
    const unsigned short* __restrict__ Bf,   // [2][KT][32][64][8]
    const float* __restrict__ bl, const float* __restrict__ br,
    float* __restrict__ C)
{
    __shared__ unsigned short Af[2][8][64][8];   // 16 KB: [part][mtile][lane][8]
    const int tid  = threadIdx.x;
    const int lane = tid & 63;
    const int w    = tid >> 6;
    const int m0   = blockIdx.x * 128;
    const int n0   = blockIdx.y * 128;
    const int KT   = K >> 5;
    const int ntg0 = n0 >> 4;

    f32x4 acc[2][8];
    #pragma unroll
    for (int i = 0; i < 2; ++i)
        #pragma unroll
        for (int j = 0; j < 8; ++j) acc[i][j] = (f32x4){0.f, 0.f, 0.f, 0.f};

    const size_t partStride = (size_t)KT * 32 * 512;   // shorts

    for (int kt = 0; kt < KT; ++kt) {
        // ---- stage A tile (128x32 fp32 -> hi/lo bf16 frags in LDS) ----
        #pragma unroll
        for (int i = 0; i < 4; ++i) {
            int idx = tid * 4 + i;          // 0..1023 float4s
            int r   = idx >> 3;             // row 0..127
            int kl  = (idx & 7) * 4;        // k_local 0..28
            int gm  = m0 + r;
            float4 v = make_float4(0.f, 0.f, 0.f, 0.f);
            if (gm < M) v = *(const float4*)(A + (size_t)gm * K + kt * 32 + kl);
            unsigned short h0 = bf16hi(v.x), h1 = bf16hi(v.y);
            unsigned short h2 = bf16hi(v.z), h3 = bf16hi(v.w);
            unsigned short l0 = bf16hi(v.x - bf16tof(h0));
            unsigned short l1 = bf16hi(v.y - bf16tof(h1));
            unsigned short l2 = bf16hi(v.z - bf16tof(h2));
            unsigned short l3 = bf16hi(v.w - bf16tof(h3));
            int mt = r >> 4;
            int la = (r & 15) | ((kl >> 3) << 4);
            int j0 = kl & 7;
            *(uint2*)&Af[0][mt][la][j0] =
                make_uint2((unsigned int)h0 | ((unsigned int)h1 << 16),
                           (unsigned int)h2 | ((unsigned int)h3 << 16));
            *(uint2*)&Af[1][mt][la][j0] =
                make_uint2((unsigned int)l0 | ((unsigned int)l1 << 16),
                           (unsigned int)l2 | ((unsigned int)l3 << 16));
        }
        __syncthreads();

        bf16x8 ah0 = *(const bf16x8*)&Af[0][w * 2 + 0][lane][0];
        bf16x8 ah1 = *(const bf16x8*)&Af[0][w * 2 + 1][lane][0];
        bf16x8 al0 = *(const bf16x8*)&Af[1][w * 2 + 0][lane][0];
        bf16x8 al1 = *(const bf16x8*)&Af[1][w * 2 + 1][lane][0];

        const unsigned short* bbase =
            Bf + ((size_t)kt * 32 + ntg0) * 512 + (size_t)lane * 8;
        #pragma unroll
        for (int nt = 0; nt < 8; ++nt) {
            bf16x8 bh  = *(const bf16x8*)(bbase + (size_t)nt * 512);
            bf16x8 blv = *(const bf16x8*)(bbase + partStride + (size_t)nt * 512);
            acc[0][nt] = __builtin_amdgcn_mfma_f32_16x16x32_bf16(ah0, bh,  acc[0][nt], 0, 0, 0);
            acc[1][nt] = __builtin_amdgcn_mfma_f32_16x16x32_bf16(ah1, bh,  acc[1][nt], 0, 0, 0);
            acc[0][nt] = __builtin_amdgcn_mfma_f32_16x16x32_bf16(ah0, blv, acc[0][nt], 0, 0, 0);
            acc[1][nt] = __builtin_amdgcn_mfma_f32_16x16x32_bf16(ah1, blv, acc[1][nt], 0, 0, 0);
            acc[0][nt] = __builtin_amdgcn_mfma_f32_16x16x32_bf16(al0, bh,  acc[0][nt], 0, 0, 0);
            acc[1][nt] = __builtin_amdgcn_mfma_f32_16x16x32_bf16(al1, bh,  acc[1][nt], 0, 0, 0);
        }
        __syncthreads();
    }

    // ---- epilogue: D row=(lane>>4)*4+r, col=lane&15 ----
    const int q  = lane >> 4;
    const int cl = lane & 15;
    #pragma unroll
    for (int mti = 0; mti < 2; ++mti) {
        int gmb = m0 + (w * 2 + mti) * 16 + q * 4;
        #pragma unroll
        for (int nt = 0; nt < 8; ++nt) {
            int col = n0 + nt * 16 + cl;
            float bia = (col < 256) ? bl[col] : br[col - 256];
            #pragma unroll
            for (int r = 0; r < 4; ++r) {
                int gm = gmb + r;
                if (gm < M) C[(size_t)gm * 512 + col] = acc[mti][nt][r] + bia;
            }
        }
    }
}

// ---------------------------------------------------------------------------
// FUSED logit + aggregate. One wave per dst node. Per 16-edge CSR chunk:
//  Phase A (logit): MFMA ea term (3-part hi/lo split, identical numerics to
//    the previous logit_kernel), fp32 xl[src]/xr[n] adds, leaky_relu, dot
//    with att, q-lane shuffle reduce -> logit; p = exp(logit) (no-max
//    softmax, shift-invariant & validated). p + src cached in per-wave LDS.
//  Phase B (aggregate): re-gather the SAME xl rows (L2-hot: same wave ->
//    same XCD, read moments earlier) and accumulate acc += p*xl4 per lane.
// This halves the unique L3-side gather traffic vs separate kernels and
// removes the logits buffer entirely. PROJ fuses the final W_out projection.
// No occupancy attributes: r1-r3 showed any forced VGPR cap spills 1:1.
// ---------------------------------------------------------------------------
template<bool PROJ>
__global__ __launch_bounds__(256) void gat_fused_t(
    const float* __restrict__ xlxr,       // [N,512]
    const float* __restrict__ edge_attr,  // [E,32]
    const int* __restrict__ col_src,      // [E] CSR order
    const int* __restrict__ col_eid,      // [E] CSR order
    const int* __restrict__ row_ptr,      // [N+1]
    const unsigned short* __restrict__ WePl, // hi @0, lo @+8192 shorts
    const float* __restrict__ att,        // [256]
    const float* __restrict__ bias,       // [256]
    float* __restrict__ hout,             // [N,256]   (PROJ=false)
    const float* __restrict__ Wout,       // [256]     (PROJ=true)
    const float* __restrict__ bout,       // [1]       (PROJ=true)
    float* __restrict__ out,              // [N,1]     (PROJ=true)
    int N)
{
    __shared__ unsigned short AloS[16][64][8];   // 16 KB: lo tiles 0..15
    __shared__ unsigned short AhiS[8][64][8];    //  8 KB: hi tiles 8..15
    __shared__ float pS[4][16][4];               //  1 KB: per-wave p[edge][head]
    __shared__ int   srcS[4][16];                // 256 B: per-wave src idx

    const int tid = threadIdx.x;
    #pragma unroll
    for (int i = 0; i < 4; ++i) {
        int idx = tid * 4 + i;                   // 1024 uint4s = 16 KB
        ((uint4*)&AloS[0][0][0])[idx] = ((const uint4*)(WePl + 8192))[idx];
    }
    #pragma unroll
    for (int i = 0; i < 2; ++i) {
        int idx = tid * 2 + i;                   // 512 uint4s = 8 KB
        ((uint4*)&AhiS[0][0][0])[idx] = ((const uint4*)WePl)[idx + 512];
    }

    const int lane  = tid & 63;
    const int wid   = tid >> 6;
    const int q     = lane >> 4;      // logit phase: k-block / head group
    const int e_sub = lane & 15;
    const int kb    = q * 8;
    const int ch0   = lane * 4;       // aggregate phase: channels 4l..4l+3
    const int h     = q;              // head of ch0 = lane>>4

    bf16x8 Ahi[8];                               // hi tiles 0..7 in regs
    #pragma unroll
    for (int t = 0; t < 8; ++t)
        Ahi[t] = *(const bf16x8*)(WePl + ((size_t)t * 64 + lane) * 8);
    __syncthreads();

    const int n = blockIdx.x * 4 + wid;
    if (n >= N) return;

    const int e0 = row_ptr[n], e1 = row_ptr[n + 1];
    const float* xrp = xlxr + (size_t)n * 512 + 256 + q * 4;

    float denom = 0.f;
    float4 acc = make_float4(0.f, 0.f, 0.f, 0.f);

    for (int base = e0; base < e1; base += 16) {
        // ================= Phase A: logits for edges base..base+15 =========
        const int slot = base + e_sub;
        const int sc   = min(slot, e1 - 1);
        const int eid  = col_eid[sc];
        const int srcn = col_src[sc];
        if (q == 0) srcS[wid][e_sub] = srcn;

        const float* ap = edge_attr + (size_t)eid * 32 + kb;
        float4 v0 = *(const float4*)ap;
        float4 v1 = *(const float4*)(ap + 4);
        float vv[8] = {v0.x, v0.y, v0.z, v0.w, v1.x, v1.y, v1.z, v1.w};
        union { bf16x8 v; unsigned short u[8]; } bh, bl;
        #pragma unroll
        for (int i = 0; i < 8; ++i) {
            unsigned short hh = bf16hi(vv[i]);
            bh.u[i] = hh;
            bl.u[i] = bf16hi(vv[i] - bf16tof(hh));
        }

        const float* xlp = xlxr + (size_t)srcn * 512 + q * 4;

        float lph[4] = {0.f, 0.f, 0.f, 0.f};
        #pragma unroll
        for (int t = 0; t < 16; ++t) {
            bf16x8 ahi = (t < 8) ? Ahi[t & 7]
                                 : *(const bf16x8*)&AhiS[t & 7][lane][0];
            bf16x8 alo = *(const bf16x8*)&AloS[t][lane][0];
            f32x4 macc = {0.f, 0.f, 0.f, 0.f};
            macc = __builtin_amdgcn_mfma_f32_16x16x32_bf16(ahi, bh.v, macc, 0, 0, 0);
            macc = __builtin_amdgcn_mfma_f32_16x16x32_bf16(ahi, bl.v, macc, 0, 0, 0);
            macc = __builtin_amdgcn_mfma_f32_16x16x32_bf16(alo, bh.v, macc, 0, 0, 0);
            const float4 xl4 = *(const float4*)(xlp + t * 16);
            const float4 xr4 = *(const float4*)(xrp + t * 16);
            const float4 at4 = *(const float4*)(att + t * 16 + q * 4);
            float z0 = macc[0] + xl4.x + xr4.x; z0 = (z0 > 0.f) ? z0 : NEG_SLOPE * z0;
            float z1 = macc[1] + xl4.y + xr4.y; z1 = (z1 > 0.f) ? z1 : NEG_SLOPE * z1;
            float z2 = macc[2] + xl4.z + xr4.z; z2 = (z2 > 0.f) ? z2 : NEG_SLOPE * z2;
            float z3 = macc[3] + xl4.w + xr4.w; z3 = (z3 > 0.f) ? z3 : NEG_SLOPE * z3;
            float s = z0 * at4.x;
            s = fmaf(z1, at4.y, s);
            s = fmaf(z2, at4.z, s);
            s = fmaf(z3, at4.w, s);
            lph[t >> 2] += s;
        }
        #pragma unroll
        for (int hh = 0; hh < 4; ++hh) {
            lph[hh] += __shfl_xor(lph[hh], 16, 64);
            lph[hh] += __shfl_xor(lph[hh], 32, 64);
        }
        // p = exp(logit), 0 for inactive tail slots; stash per-wave
        if (q == 0) {
            float4 pv;
            pv.x = (slot < e1) ? __expf(lph[0]) : 0.f;
            pv.y = (slot < e1) ? __expf(lph[1]) : 0.f;
            pv.z = (slot < e1) ? __expf(lph[2]) : 0.f;
            pv.w = (slot < e1) ? __expf(lph[3]) : 0.f;
            *(float4*)&pS[wid][e_sub][0] = pv;
        }
        // same-wave LDS write->read: DS pipeline is in-order per wave; the
        // compiler inserts the lgkmcnt wait on the dependent ds_read.

        // ================= Phase B: aggregate (xl rows are L2-hot) =========
        const int nv = min(16, e1 - base);
        for (int e = 0; e < nv; e += 4) {
            int   sidx[4];
            float pe[4];
            #pragma unroll
            for (int i = 0; i < 4; ++i) {
                int ee = e + i;
                int ec = (ee < nv) ? ee : nv - 1;
                sidx[i] = srcS[wid][ec];
                pe[i]   = (ee < nv) ? pS[wid][ec][h] : 0.f;
            }
            float4 xv[4];
            #pragma unroll
            for (int i = 0; i < 4; ++i)
                xv[i] = *(const float4*)(xlxr + (size_t)sidx[i] * 512 + ch0);
            #pragma unroll
            for (int i = 0; i < 4; ++i) {
                denom += pe[i];
                acc.x = fmaf(pe[i], xv[i].x, acc.x);
                acc.y = fmaf(pe[i], xv[i].y, acc.y);
                acc.z = fmaf(pe[i], xv[i].z, acc.z);
                acc.w = fmaf(pe[i], xv[i].w, acc.w);
            }
        }
    }

    // ---- epilogue: normalize, bias, relu, store / project ----
    const float inv = (e1 > e0) ? 1.0f / denom : 0.f;
    const float4 b4 = *(const float4*)(bias + ch0);
    float4 o;
    o.x = fmaxf(fmaf(acc.x, inv, b4.x), 0.f);
    o.y = fmaxf(fmaf(acc.y, inv, b4.y), 0.f);
    o.z = fmaxf(fmaf(acc.z, inv, b4.z), 0.f);
    o.w = fmaxf(fmaf(acc.w, inv, b4.w), 0.f);

    if (!PROJ) {
        *(float4*)(hout + (size_t)n * 256 + ch0) = o;
    } else {
        const float4 w4 = *(const float4*)(Wout + ch0);
        float s = o.x * w4.x;
        s = fmaf(o.y, w4.y, s);
        s = fmaf(o.z, w4.z, s);
        s = fmaf(o.w, w4.w, s);
        #pragma unroll
        for (int off = 32; off > 0; off >>= 1)
            s += __shfl_xor(s, off, 64);
        if (lane == 0) out[n] = s + bout[0];
    }
}

// ---------------------------------------------------------------------------
extern "C" void kernel_launch(void* const* d_in, const int* in_sizes, int n_in,
                              void* d_out, int out_size, void* d_ws, size_t ws_size,
                              hipStream_t stream) {
    const float* x         = (const float*)d_in[0];
    const int*   edge_idx  = (const int*)d_in[1];
    const float* edge_attr = (const float*)d_in[2];
    const float* W_l0 = (const float*)d_in[3];
    const float* b_l0 = (const float*)d_in[4];
    const float* W_r0 = (const float*)d_in[5];
    const float* b_r0 = (const float*)d_in[6];
    const float* W_e0 = (const float*)d_in[7];
    const float* att0 = (const float*)d_in[8];
    const float* bias0= (const float*)d_in[9];
    const float* W_l1 = (const float*)d_in[10];
    const float* b_l1 = (const float*)d_in[11];
    const float* W_r1 = (const float*)d_in[12];
    const float* b_r1 = (const float*)d_in[13];
    const float* W_e1 = (const float*)d_in[14];
    const float* att1 = (const float*)d_in[15];
    const float* bias1= (const float*)d_in[16];
    const float* W_out= (const float*)d_in[17];
    const float* b_out= (const float*)d_in[18];

    const int N = in_sizes[0] / 512;      // 50000
    const int E = in_sizes[1] / 2;        // 800000

    const int* src = edge_idx;
    const int* dst = edge_idx + E;

    // workspace layout
    char* ws = (char*)d_ws;
    size_t off = 0;
    float* bufA   = (float*)(ws + off); off += (size_t)N * 512 * 4;   // 102.4 MB
    float* bufB   = (float*)(ws + off); off += (size_t)N * 256 * 4;   //  51.2 MB
    int* row_ptr  = (int*)(ws + off);   off += (((size_t)(N + 1) * 4 + 255) & ~(size_t)255);
    int* cursor   = (int*)(ws + off);   off += (((size_t)N * 4 + 255) & ~(size_t)255);
    int* col_src  = (int*)(ws + off);   off += (size_t)E * 4;
    int* col_eid  = (int*)(ws + off);   off += (size_t)E * 4;
    int* totals   = (int*)(ws + off);   off += 1024;
    unsigned short* WeP = (unsigned short*)(ws + off); off += 4096 * 8 * 2;        // 64 KB
    unsigned short* Bf0 = (unsigned short*)(ws + off); off += (size_t)2 * 16 * 32 * 64 * 8 * 2; // 1 MB
    unsigned short* Bf1 = (unsigned short*)(ws + off); off += (size_t)2 * 8 * 32 * 64 * 8 * 2;  // 512 KB

    const int nbE = (E + 255) / 256;
    const int nbN = (N + 255) / 256;

    // ---- CSR build + weight prepack ----
    hipMemsetAsync(cursor, 0, (size_t)N * 4, stream);
    hist_kernel<<<nbE, 256, 0, stream>>>(dst, cursor, E);
    scan_s1<<<nbN, 256, 0, stream>>>(cursor, row_ptr, totals, N);
    scan_s2<<<1, 256, 0, stream>>>(totals, nbN);
    scan_s3<<<nbN, 256, 0, stream>>>(row_ptr, totals, cursor, N, E);
    scatter_kernel<<<nbE, 256, 0, stream>>>(src, dst, cursor, col_src, col_eid, E);
    pack_we<<<16, 256, 0, stream>>>(W_e0, W_e1, WeP);
    pack_w<<<256, 256, 0, stream>>>(W_l0, W_r0, 16, Bf0);
    pack_w<<<128, 256, 0, stream>>>(W_l1, W_r1, 8, Bf1);

    dim3 ggrid((N + 127) / 128, 4);
    const int ngat = (N + 3) / 4;

    // ---- Layer 0 ----
    gemm_split<<<ggrid, 256, 0, stream>>>(x, N, 512, Bf0, b_l0, b_r0, bufA);
    gat_fused_t<false><<<ngat, 256, 0, stream>>>(
        bufA, edge_attr, col_src, col_eid, row_ptr, WeP, att0, bias0,
        bufB, nullptr, nullptr, nullptr, N);

    // ---- Layer 1 ----
    gemm_split<<<ggrid, 256, 0, stream>>>(bufB, N, 256, Bf1, b_l1, b_r1, bufA);
    gat_fused_t<true><<<ngat, 256, 0, stream>>>(
        bufA, edge_attr, col_src, col_eid, row_ptr, WeP + 16384, att1, bias1,
        nullptr, W_out, b_out, (float*)d_out, N);
}

// Round 6
// 1382.422 us; speedup vs baseline: 1.3927x; 1.3927x over previous
//
#include <hip/hip_runtime.h>
#include <hip/hip_bf16.h>

#define NEG_SLOPE 0.2f

typedef __attribute__((ext_vector_type(8))) short bf16x8;
typedef __attribute__((ext_vector_type(4))) float f32x4;

__device__ __forceinline__ unsigned short bf16hi(float v) {
    __hip_bfloat16 h = __float2bfloat16(v);
    return *(unsigned short*)&h;
}
__device__ __forceinline__ float bf16tof(unsigned short u) {
    __hip_bfloat16 h = *(__hip_bfloat16*)&u;
    return __bfloat162float(h);
}

// ---------------------------------------------------------------------------
// CSR build
// ---------------------------------------------------------------------------
__global__ void hist_kernel(const int* __restrict__ dst, int* __restrict__ cnt, int E) {
    int e = blockIdx.x * 256 + threadIdx.x;
    if (e < E) atomicAdd(&cnt[dst[e]], 1);
}

__global__ void scan_s1(const int* __restrict__ cnt, int* __restrict__ excl,
                        int* __restrict__ totals, int N) {
    __shared__ int lds[256];
    int t = threadIdx.x;
    int i = blockIdx.x * 256 + t;
    int v = (i < N) ? cnt[i] : 0;
    lds[t] = v;
    __syncthreads();
    #pragma unroll
    for (int off = 1; off < 256; off <<= 1) {
        int add = (t >= off) ? lds[t - off] : 0;
        __syncthreads();
        lds[t] += add;
        __syncthreads();
    }
    if (i < N) excl[i] = lds[t] - v;
    if (t == 255) totals[blockIdx.x] = lds[255];
}

__global__ void scan_s2(int* __restrict__ totals, int nb) {
    __shared__ int lds[256];
    int t = threadIdx.x;
    int v = (t < nb) ? totals[t] : 0;
    lds[t] = v;
    __syncthreads();
    #pragma unroll
    for (int off = 1; off < 256; off <<= 1) {
        int add = (t >= off) ? lds[t - off] : 0;
        __syncthreads();
        lds[t] += add;
        __syncthreads();
    }
    if (t < nb) totals[t] = lds[t] - v;   // exclusive over block totals
}

__global__ void scan_s3(int* __restrict__ row_ptr, const int* __restrict__ totals,
                        int* __restrict__ cursor, int N, int E) {
    int i = blockIdx.x * 256 + threadIdx.x;
    if (i < N) {
        int v = row_ptr[i] + totals[blockIdx.x];
        row_ptr[i] = v;
        cursor[i] = v;
    }
    if (i == 0) row_ptr[N] = E;
}

__global__ void scatter_kernel(const int* __restrict__ src, const int* __restrict__ dst,
                               int* __restrict__ cursor, int* __restrict__ col_src,
                               int* __restrict__ col_dst, int* __restrict__ col_eid, int E) {
    int e = blockIdx.x * 256 + threadIdx.x;
    if (e < E) {
        int d = dst[e];
        int pos = atomicAdd(&cursor[d], 1);
        col_src[pos] = src[e];
        col_dst[pos] = d;
        col_eid[pos] = e;
    }
}

// ---------------------------------------------------------------------------
// Pack We (fp32 [32,256]) into MFMA A-fragment order, bf16 hi + lo parts.
// WeP layout: [layer][part][tile][lane][8] shorts; layer stride 16384,
// lo part at +8192. A[m=lane&15][k=(lane>>4)*8+j].
// ---------------------------------------------------------------------------
__global__ void pack_we(const float* __restrict__ We0, const float* __restrict__ We1,
                        unsigned short* __restrict__ WeP) {
    int t = blockIdx.x * 256 + threadIdx.x;
    if (t >= 4096) return;
    int layer = t >> 11;
    int part  = (t >> 10) & 1;
    int tile  = (t >> 6) & 15;
    int lane  = t & 63;
    const float* We = layer ? We1 : We0;
    int ch = tile * 16 + (lane & 15);
    int kb = (lane >> 4) * 8;
    union { unsigned short u[8]; uint4 v; } out;
    #pragma unroll
    for (int j = 0; j < 8; ++j) {
        float w = We[(size_t)(kb + j) * 256 + ch];
        unsigned short hi = bf16hi(w);
        out.u[j] = part ? bf16hi(w - bf16tof(hi)) : hi;
    }
    *(uint4*)(WeP + (size_t)t * 8) = out.v;
}

// ---------------------------------------------------------------------------
// Pack W = [Wl | Wr] (fp32 [K,256] each) into MFMA B-frag order, hi+lo bf16.
// Layout: [part(2)][kt(KT)][ntglob(32)][lane(64)][8] shorts.
// B[n=nt*16+(lane&15)][k=kt*32+(lane>>4)*8+j].
// ---------------------------------------------------------------------------
__global__ void pack_w(const float* __restrict__ Wl, const float* __restrict__ Wr,
                       int KT, unsigned short* __restrict__ out) {
    int t = blockIdx.x * 256 + threadIdx.x;
    int per = KT * 2048;             // KT*32*64
    if (t >= 2 * per) return;
    int part = t / per;
    int rem  = t % per;
    int kt   = rem >> 11;
    int nt   = (rem >> 6) & 31;
    int lane = rem & 63;
    int n  = nt * 16 + (lane & 15);
    int kb = kt * 32 + ((lane >> 4) * 8);
    const float* W = (n < 256) ? (Wl + n) : (Wr + (n - 256));
    union { unsigned short u[8]; uint4 v; } o;
    #pragma unroll
    for (int j = 0; j < 8; ++j) {
        float w = W[(size_t)(kb + j) * 256];
        unsigned short hi = bf16hi(w);
        o.u[j] = part ? bf16hi(w - bf16tof(hi)) : hi;
    }
    *(uint4*)(out + (size_t)t * 8) = o.v;
}

// ---------------------------------------------------------------------------
// Split-bf16 MFMA GEMM: C[M,512] = A[M,K] @ [Wl|Wr] + [bl|br], fp32-accurate
// via 3-term hi/lo split. Block = 128 rows x 128 cols, 4 waves; wave handles
// 2 row-tiles x 8 col-tiles. A staged to LDS as hi/lo bf16 frags per K-step.
// ---------------------------------------------------------------------------
__global__ __launch_bounds__(256) void gemm_split(
    const float* __restrict__ A, int M, int K,
    const unsigned short* __restrict__ Bf,   // [2][KT][32][64][8]
    const float* __restrict__ bl, const float* __restrict__ br,
    float* __restrict__ C)
{
    __shared__ unsigned short Af[2][8][64][8];   // 16 KB: [part][mtile][lane][8]
    const int tid  = threadIdx.x;
    const int lane = tid & 63;
    const int w    = tid >> 6;
    const int m0   = blockIdx.x * 128;
    const int n0   = blockIdx.y * 128;
    const int KT   = K >> 5;
    const int ntg0 = n0 >> 4;

    f32x4 acc[2][8];
    #pragma unroll
    for (int i = 0; i < 2; ++i)
        #pragma unroll
        for (int j = 0; j < 8; ++j) acc[i][j] = (f32x4){0.f, 0.f, 0.f, 0.f};

    const size_t partStride = (size_t)KT * 32 * 512;   // shorts

    for (int kt = 0; kt < KT; ++kt) {
        // ---- stage A tile (128x32 fp32 -> hi/lo bf16 frags in LDS) ----
        #pragma unroll
        for (int i = 0; i < 4; ++i) {
            int idx = tid * 4 + i;          // 0..1023 float4s
            int r   = idx >> 3;             // row 0..127
            int kl  = (idx & 7) * 4;        // k_local 0..28
            int gm  = m0 + r;
            float4 v = make_float4(0.f, 0.f, 0.f, 0.f);
            if (gm < M) v = *(const float4*)(A + (size_t)gm * K + kt * 32 + kl);
            unsigned short h0 = bf16hi(v.x), h1 = bf16hi(v.y);
            unsigned short h2 = bf16hi(v.z), h3 = bf16hi(v.w);
            unsigned short l0 = bf16hi(v.x - bf16tof(h0));
            unsigned short l1 = bf16hi(v.y - bf16tof(h1));
            unsigned short l2 = bf16hi(v.z - bf16tof(h2));
            unsigned short l3 = bf16hi(v.w - bf16tof(h3));
            int mt = r >> 4;
            int la = (r & 15) | ((kl >> 3) << 4);
            int j0 = kl & 7;
            *(uint2*)&Af[0][mt][la][j0] =
                make_uint2((unsigned int)h0 | ((unsigned int)h1 << 16),
                           (unsigned int)h2 | ((unsigned int)h3 << 16));
            *(uint2*)&Af[1][mt][la][j0] =
                make_uint2((unsigned int)l0 | ((unsigned int)l1 << 16),
                           (unsigned int)l2 | ((unsigned int)l3 << 16));
        }
        __syncthreads();

        bf16x8 ah0 = *(const bf16x8*)&Af[0][w * 2 + 0][lane][0];
        bf16x8 ah1 = *(const bf16x8*)&Af[0][w * 2 + 1][lane][0];
        bf16x8 al0 = *(const bf16x8*)&Af[1][w * 2 + 0][lane][0];
        bf16x8 al1 = *(const bf16x8*)&Af[1][w * 2 + 1][lane][0];

        const unsigned short* bbase =
            Bf + ((size_t)kt * 32 + ntg0) * 512 + (size_t)lane * 8;
        #pragma unroll
        for (int nt = 0; nt < 8; ++nt) {
            bf16x8 bh  = *(const bf16x8*)(bbase + (size_t)nt * 512);
            bf16x8 blv = *(const bf16x8*)(bbase + partStride + (size_t)nt * 512);
            acc[0][nt] = __builtin_amdgcn_mfma_f32_16x16x32_bf16(ah0, bh,  acc[0][nt], 0, 0, 0);
            acc[1][nt] = __builtin_amdgcn_mfma_f32_16x16x32_bf16(ah1, bh,  acc[1][nt], 0, 0, 0);
            acc[0][nt] = __builtin_amdgcn_mfma_f32_16x16x32_bf16(ah0, blv, acc[0][nt], 0, 0, 0);
            acc[1][nt] = __builtin_amdgcn_mfma_f32_16x16x32_bf16(ah1, blv, acc[1][nt], 0, 0, 0);
            acc[0][nt] = __builtin_amdgcn_mfma_f32_16x16x32_bf16(al0, bh,  acc[0][nt], 0, 0, 0);
            acc[1][nt] = __builtin_amdgcn_mfma_f32_16x16x32_bf16(al1, bh,  acc[1][nt], 0, 0, 0);
        }
        __syncthreads();
    }

    // ---- epilogue: D row=(lane>>4)*4+r, col=lane&15 ----
    const int q  = lane >> 4;
    const int cl = lane & 15;
    #pragma unroll
    for (int mti = 0; mti < 2; ++mti) {
        int gmb = m0 + (w * 2 + mti) * 16 + q * 4;
        #pragma unroll
        for (int nt = 0; nt < 8; ++nt) {
            int col = n0 + nt * 16 + cl;
            float bia = (col < 256) ? bl[col] : br[col - 256];
            #pragma unroll
            for (int r = 0; r < 4; ++r) {
                int gm = gmb + r;
                if (gm < M) C[(size_t)gm * 512 + col] = acc[mti][nt][r] + bia;
            }
        }
    }
}

// ---------------------------------------------------------------------------
// Pass 1: per-edge attention logits [E,4] in CSR slot order (r4 structure —
// best measured: 297 us, VGPR 180 natural, spill-free, 2 waves/SIMD).
// One wave handles 16 edges. ea via 3-term hi/lo bf16 MFMA. We-hi tiles 0..7
// in registers; hi 8..15 + all lo tiles in LDS. No occupancy attributes:
// r1/r2/r3 showed any forced VGPR cap converts registers into scratch 1:1.
// ---------------------------------------------------------------------------
__global__ __launch_bounds__(256) void logit_kernel(
    const float* __restrict__ xlxr,       // [N,512]
    const float* __restrict__ edge_attr,  // [E,32]
    const int* __restrict__ col_src,      // [E]
    const int* __restrict__ col_dst,      // [E]
    const int* __restrict__ col_eid,      // [E]
    const unsigned short* __restrict__ WePl, // hi @0, lo @+8192 shorts
    const float* __restrict__ att,        // [256]
    float* __restrict__ logits,           // [E,4]
    int E)
{
    __shared__ unsigned short AloS[16][64][8];   // 16 KB: lo tiles 0..15
    __shared__ unsigned short AhiS[8][64][8];    //  8 KB: hi tiles 8..15
    const int tid = threadIdx.x;
    #pragma unroll
    for (int i = 0; i < 4; ++i) {
        int idx = tid * 4 + i;                   // 1024 uint4s = 16 KB
        ((uint4*)&AloS[0][0][0])[idx] = ((const uint4*)(WePl + 8192))[idx];
    }
    #pragma unroll
    for (int i = 0; i < 2; ++i) {
        int idx = tid * 2 + i;                   // 512 uint4s = 8 KB
        ((uint4*)&AhiS[0][0][0])[idx] = ((const uint4*)WePl)[idx + 512];
    }

    const int lane  = tid & 63;
    const int q     = lane >> 4;
    const int e_sub = lane & 15;
    const int kb    = q * 8;

    bf16x8 Ahi[8];                               // hi tiles 0..7 in regs
    #pragma unroll
    for (int t = 0; t < 8; ++t)
        Ahi[t] = *(const bf16x8*)(WePl + ((size_t)t * 64 + lane) * 8);
    __syncthreads();

    const int gw = blockIdx.x * 4 + (tid >> 6);
    const int nw = gridDim.x * 4;
    const int nb = (E + 15) >> 4;

    for (int b = gw; b < nb; b += nw) {
        const int slot = b * 16 + e_sub;
        const int sc   = min(slot, E - 1);
        const int eid  = col_eid[sc];
        const int srcn = col_src[sc];
        const int dstn = col_dst[sc];

        const float* ap = edge_attr + (size_t)eid * 32 + kb;
        float4 v0 = *(const float4*)ap;
        float4 v1 = *(const float4*)(ap + 4);
        float vv[8] = {v0.x, v0.y, v0.z, v0.w, v1.x, v1.y, v1.z, v1.w};
        union { bf16x8 v; unsigned short u[8]; } bh, bl;
        #pragma unroll
        for (int i = 0; i < 8; ++i) {
            unsigned short h = bf16hi(vv[i]);
            bh.u[i] = h;
            bl.u[i] = bf16hi(vv[i] - bf16tof(h));
        }

        const float* xlp = xlxr + (size_t)srcn * 512 + q * 4;
        const float* xrp = xlxr + (size_t)dstn * 512 + 256 + q * 4;

        float lph[4] = {0.f, 0.f, 0.f, 0.f};
        #pragma unroll
        for (int t = 0; t < 16; ++t) {
            bf16x8 ahi = (t < 8) ? Ahi[t & 7]
                                 : *(const bf16x8*)&AhiS[t & 7][lane][0];
            bf16x8 alo = *(const bf16x8*)&AloS[t][lane][0];
            f32x4 acc = {0.f, 0.f, 0.f, 0.f};
            acc = __builtin_amdgcn_mfma_f32_16x16x32_bf16(ahi, bh.v, acc, 0, 0, 0);
            acc = __builtin_amdgcn_mfma_f32_16x16x32_bf16(ahi, bl.v, acc, 0, 0, 0);
            acc = __builtin_amdgcn_mfma_f32_16x16x32_bf16(alo, bh.v, acc, 0, 0, 0);
            const float4 xl4 = *(const float4*)(xlp + t * 16);
            const float4 xr4 = *(const float4*)(xrp + t * 16);
            const float4 at4 = *(const float4*)(att + t * 16 + q * 4);
            float z0 = acc[0] + xl4.x + xr4.x; z0 = (z0 > 0.f) ? z0 : NEG_SLOPE * z0;
            float z1 = acc[1] + xl4.y + xr4.y; z1 = (z1 > 0.f) ? z1 : NEG_SLOPE * z1;
            float z2 = acc[2] + xl4.z + xr4.z; z2 = (z2 > 0.f) ? z2 : NEG_SLOPE * z2;
            float z3 = acc[3] + xl4.w + xr4.w; z3 = (z3 > 0.f) ? z3 : NEG_SLOPE * z3;
            float s = z0 * at4.x;
            s = fmaf(z1, at4.y, s);
            s = fmaf(z2, at4.z, s);
            s = fmaf(z3, at4.w, s);
            lph[t >> 2] += s;
        }
        #pragma unroll
        for (int h = 0; h < 4; ++h) {
            lph[h] += __shfl_xor(lph[h], 16, 64);
            lph[h] += __shfl_xor(lph[h], 32, 64);
        }
        if (q == 0 && slot < E) {
            float4 o = make_float4(lph[0], lph[1], lph[2], lph[3]);
            *(float4*)(logits + (size_t)slot * 4) = o;
        }
    }
}

// ---------------------------------------------------------------------------
// Pass 2: aggregation, 16 lanes per node / 4 nodes per wave.
// Lane owns 16 contiguous channels (64 B) of its node: a row-read is 16
// lanes x 4 float4s; with a 4-wide edge unroll the wave has 16 rows
// (~16 KB) in flight vs 8 KB in the one-node-per-wave version -> attacks
// the MLP/latency limit seen at ~2.7 TB/s. 4 nodes/wave also smooths
// degree stragglers. No-max softmax (shift-invariant, validated r3/r4).
// PROJ fuses the final W_out projection (16-lane shuffle reduce).
// ---------------------------------------------------------------------------
template<bool PROJ>
__global__ __launch_bounds__(256) void aggregate16_t(
    const float* __restrict__ xlxr,     // [N,512]
    const float* __restrict__ logits,   // [E,4] CSR order
    const int* __restrict__ col_src,    // [E]
    const int* __restrict__ row_ptr,    // [N+1]
    const float* __restrict__ bias,     // [256]
    float* __restrict__ hout,           // [N,256]   (PROJ=false)
    const float* __restrict__ Wout,     // [256]     (PROJ=true)
    const float* __restrict__ bout,     // [1]       (PROJ=true)
    float* __restrict__ out,            // [N,1]     (PROJ=true)
    int N)
{
    const int tid  = threadIdx.x;
    const int lane = tid & 63;
    const int wid  = tid >> 6;
    const int g    = lane >> 4;          // node group within wave
    const int l16  = lane & 15;
    const int n    = blockIdx.x * 16 + wid * 4 + g;
    const int head = l16 >> 2;           // 16 ch/lane, 64 ch/head
    const int ch0  = l16 * 16;           // float index of first owned channel

    int e0 = 0, e1 = 0;
    if (n < N) { e0 = row_ptr[n]; e1 = row_ptr[n + 1]; }

    float denom = 0.f;
    float4 a0 = {0,0,0,0}, a1 = {0,0,0,0}, a2 = {0,0,0,0}, a3 = {0,0,0,0};

    for (int j = e0; j < e1; j += 4) {
        int   sidx[4];
        float p[4];
        #pragma unroll
        for (int i = 0; i < 4; ++i) {
            int jj = j + i;
            int jc = (jj < e1) ? jj : e1 - 1;
            sidx[i] = col_src[jc];
            float lg = logits[(size_t)jc * 4 + head];
            p[i] = (jj < e1) ? __expf(lg) : 0.f;
        }
        float4 xv[4][4];
        #pragma unroll
        for (int i = 0; i < 4; ++i) {
            const float* bp = xlxr + (size_t)sidx[i] * 512 + ch0;
            xv[i][0] = *(const float4*)(bp + 0);
            xv[i][1] = *(const float4*)(bp + 4);
            xv[i][2] = *(const float4*)(bp + 8);
            xv[i][3] = *(const float4*)(bp + 12);
        }
        #pragma unroll
        for (int i = 0; i < 4; ++i) {
            denom += p[i];
            a0.x = fmaf(p[i], xv[i][0].x, a0.x);
            a0.y = fmaf(p[i], xv[i][0].y, a0.y);
            a0.z = fmaf(p[i], xv[i][0].z, a0.z);
            a0.w = fmaf(p[i], xv[i][0].w, a0.w);
            a1.x = fmaf(p[i], xv[i][1].x, a1.x);
            a1.y = fmaf(p[i], xv[i][1].y, a1.y);
            a1.z = fmaf(p[i], xv[i][1].z, a1.z);
            a1.w = fmaf(p[i], xv[i][1].w, a1.w);
            a2.x = fmaf(p[i], xv[i][2].x, a2.x);
            a2.y = fmaf(p[i], xv[i][2].y, a2.y);
            a2.z = fmaf(p[i], xv[i][2].z, a2.z);
            a2.w = fmaf(p[i], xv[i][2].w, a2.w);
            a3.x = fmaf(p[i], xv[i][3].x, a3.x);
            a3.y = fmaf(p[i], xv[i][3].y, a3.y);
            a3.z = fmaf(p[i], xv[i][3].z, a3.z);
            a3.w = fmaf(p[i], xv[i][3].w, a3.w);
        }
    }

    const float inv = (e1 > e0) ? 1.0f / denom : 0.f;
    const float4 b0 = *(const float4*)(bias + ch0 + 0);
    const float4 b1 = *(const float4*)(bias + ch0 + 4);
    const float4 b2 = *(const float4*)(bias + ch0 + 8);
    const float4 b3 = *(const float4*)(bias + ch0 + 12);
    float4 o0, o1, o2, o3;
    o0.x = fmaxf(fmaf(a0.x, inv, b0.x), 0.f);
    o0.y = fmaxf(fmaf(a0.y, inv, b0.y), 0.f);
    o0.z = fmaxf(fmaf(a0.z, inv, b0.z), 0.f);
    o0.w = fmaxf(fmaf(a0.w, inv, b0.w), 0.f);
    o1.x = fmaxf(fmaf(a1.x, inv, b1.x), 0.f);
    o1.y = fmaxf(fmaf(a1.y, inv, b1.y), 0.f);
    o1.z = fmaxf(fmaf(a1.z, inv, b1.z), 0.f);
    o1.w = fmaxf(fmaf(a1.w, inv, b1.w), 0.f);
    o2.x = fmaxf(fmaf(a2.x, inv, b2.x), 0.f);
    o2.y = fmaxf(fmaf(a2.y, inv, b2.y), 0.f);
    o2.z = fmaxf(fmaf(a2.z, inv, b2.z), 0.f);
    o2.w = fmaxf(fmaf(a2.w, inv, b2.w), 0.f);
    o3.x = fmaxf(fmaf(a3.x, inv, b3.x), 0.f);
    o3.y = fmaxf(fmaf(a3.y, inv, b3.y), 0.f);
    o3.z = fmaxf(fmaf(a3.z, inv, b3.z), 0.f);
    o3.w = fmaxf(fmaf(a3.w, inv, b3.w), 0.f);

    if (!PROJ) {
        if (n < N) {
            float* hp = hout + (size_t)n * 256 + ch0;
            *(float4*)(hp + 0)  = o0;
            *(float4*)(hp + 4)  = o1;
            *(float4*)(hp + 8)  = o2;
            *(float4*)(hp + 12) = o3;
        }
    } else {
        const float4 w0 = *(const float4*)(Wout + ch0 + 0);
        const float4 w1 = *(const float4*)(Wout + ch0 + 4);
        const float4 w2 = *(const float4*)(Wout + ch0 + 8);
        const float4 w3 = *(const float4*)(Wout + ch0 + 12);
        float s = o0.x * w0.x;
        s = fmaf(o0.y, w0.y, s); s = fmaf(o0.z, w0.z, s); s = fmaf(o0.w, w0.w, s);
        s = fmaf(o1.x, w1.x, s); s = fmaf(o1.y, w1.y, s);
        s = fmaf(o1.z, w1.z, s); s = fmaf(o1.w, w1.w, s);
        s = fmaf(o2.x, w2.x, s); s = fmaf(o2.y, w2.y, s);
        s = fmaf(o2.z, w2.z, s); s = fmaf(o2.w, w2.w, s);
        s = fmaf(o3.x, w3.x, s); s = fmaf(o3.y, w3.y, s);
        s = fmaf(o3.z, w3.z, s); s = fmaf(o3.w, w3.w, s);
        // reduce over the 16 lanes of this node group (xor bits 0..3)
        s += __shfl_xor(s, 1, 64);
        s += __shfl_xor(s, 2, 64);
        s += __shfl_xor(s, 4, 64);
        s += __shfl_xor(s, 8, 64);
        if (l16 == 0 && n < N) out[n] = s + bout[0];
    }
}

// ---------------------------------------------------------------------------
extern "C" void kernel_launch(void* const* d_in, const int* in_sizes, int n_in,
                              void* d_out, int out_size, void* d_ws, size_t ws_size,
                              hipStream_t stream) {
    const float* x         = (const float*)d_in[0];
    const int*   edge_idx  = (const int*)d_in[1];
    const float* edge_attr = (const float*)d_in[2];
    const float* W_l0 = (const float*)d_in[3];
    const float* b_l0 = (const float*)d_in[4];
    const float* W_r0 = (const float*)d_in[5];
    const float* b_r0 = (const float*)d_in[6];
    const float* W_e0 = (const float*)d_in[7];
    const float* att0 = (const float*)d_in[8];
    const float* bias0= (const float*)d_in[9];
    const float* W_l1 = (const float*)d_in[10];
    const float* b_l1 = (const float*)d_in[11];
    const float* W_r1 = (const float*)d_in[12];
    const float* b_r1 = (const float*)d_in[13];
    const float* W_e1 = (const float*)d_in[14];
    const float* att1 = (const float*)d_in[15];
    const float* bias1= (const float*)d_in[16];
    const float* W_out= (const float*)d_in[17];
    const float* b_out= (const float*)d_in[18];

    const int N = in_sizes[0] / 512;      // 50000
    const int E = in_sizes[1] / 2;        // 800000

    const int* src = edge_idx;
    const int* dst = edge_idx + E;

    // workspace layout (~178 MB total)
    char* ws = (char*)d_ws;
    size_t off = 0;
    float* bufA   = (float*)(ws + off); off += (size_t)N * 512 * 4;   // 102.4 MB
    float* bufB   = (float*)(ws + off); off += (size_t)N * 256 * 4;   //  51.2 MB
    float* logits = (float*)(ws + off); off += (size_t)E * 4 * 4;     //  12.8 MB
    int* row_ptr  = (int*)(ws + off);   off += (((size_t)(N + 1) * 4 + 255) & ~(size_t)255);
    int* cursor   = (int*)(ws + off);   off += (((size_t)N * 4 + 255) & ~(size_t)255);
    int* col_src  = (int*)(ws + off);   off += (size_t)E * 4;
    int* col_dst  = (int*)(ws + off);   off += (size_t)E * 4;
    int* col_eid  = (int*)(ws + off);   off += (size_t)E * 4;
    int* totals   = (int*)(ws + off);   off += 1024;
    unsigned short* WeP = (unsigned short*)(ws + off); off += 4096 * 8 * 2;        // 64 KB
    unsigned short* Bf0 = (unsigned short*)(ws + off); off += (size_t)2 * 16 * 32 * 64 * 8 * 2; // 1 MB
    unsigned short* Bf1 = (unsigned short*)(ws + off); off += (size_t)2 * 8 * 32 * 64 * 8 * 2;  // 512 KB

    const int nbE = (E + 255) / 256;
    const int nbN = (N + 255) / 256;

    // ---- CSR build + weight prepack ----
    hipMemsetAsync(cursor, 0, (size_t)N * 4, stream);
    hist_kernel<<<nbE, 256, 0, stream>>>(dst, cursor, E);
    scan_s1<<<nbN, 256, 0, stream>>>(cursor, row_ptr, totals, N);
    scan_s2<<<1, 256, 0, stream>>>(totals, nbN);
    scan_s3<<<nbN, 256, 0, stream>>>(row_ptr, totals, cursor, N, E);
    scatter_kernel<<<nbE, 256, 0, stream>>>(src, dst, cursor, col_src, col_dst, col_eid, E);
    pack_we<<<16, 256, 0, stream>>>(W_e0, W_e1, WeP);
    pack_w<<<256, 256, 0, stream>>>(W_l0, W_r0, 16, Bf0);
    pack_w<<<128, 256, 0, stream>>>(W_l1, W_r1, 8, Bf1);

    dim3 ggrid((N + 127) / 128, 4);
    const int ngat16 = (N + 15) / 16;

    // ---- Layer 0 ----
    gemm_split<<<ggrid, 256, 0, stream>>>(x, N, 512, Bf0, b_l0, b_r0, bufA);
    logit_kernel<<<2048, 256, 0, stream>>>(bufA, edge_attr, col_src, col_dst, col_eid,
                                           WeP, att0, logits, E);
    aggregate16_t<false><<<ngat16, 256, 0, stream>>>(
        bufA, logits, col_src, row_ptr, bias0, bufB, nullptr, nullptr, nullptr, N);

    // ---- Layer 1 ----
    gemm_split<<<ggrid, 256, 0, stream>>>(bufB, N, 256, Bf1, b_l1, b_r1, bufA);
    logit_kernel<<<2048, 256, 0, stream>>>(bufA, edge_attr, col_src, col_dst, col_eid,
                                           WeP + 16384, att1, logits, E);
    aggregate16_t<true><<<ngat16, 256, 0, stream>>>(
        bufA, logits, col_src, row_ptr, bias1, nullptr, W_out, b_out, (float*)d_out, N);
}

// Round 7
// 1130.560 us; speedup vs baseline: 1.7030x; 1.2228x over previous
//
#include <hip/hip_runtime.h>
#include <hip/hip_bf16.h>

#define NEG_SLOPE 0.2f

typedef __attribute__((ext_vector_type(8))) short bf16x8;
typedef __attribute__((ext_vector_type(4))) float f32x4;

__device__ __forceinline__ unsigned short bf16hi(float v) {
    __hip_bfloat16 h = __float2bfloat16(v);
    return *(unsigned short*)&h;
}
__device__ __forceinline__ float bf16tof(unsigned short u) {
    __hip_bfloat16 h = *(__hip_bfloat16*)&u;
    return __bfloat162float(h);
}

// ---------------------------------------------------------------------------
// CSR build
// ---------------------------------------------------------------------------
__global__ void hist_kernel(const int* __restrict__ dst, int* __restrict__ cnt, int E) {
    int e = blockIdx.x * 256 + threadIdx.x;
    if (e < E) atomicAdd(&cnt[dst[e]], 1);
}

__global__ void scan_s1(const int* __restrict__ cnt, int* __restrict__ excl,
                        int* __restrict__ totals, int N) {
    __shared__ int lds[256];
    int t = threadIdx.x;
    int i = blockIdx.x * 256 + t;
    int v = (i < N) ? cnt[i] : 0;
    lds[t] = v;
    __syncthreads();
    #pragma unroll
    for (int off = 1; off < 256; off <<= 1) {
        int add = (t >= off) ? lds[t - off] : 0;
        __syncthreads();
        lds[t] += add;
        __syncthreads();
    }
    if (i < N) excl[i] = lds[t] - v;
    if (t == 255) totals[blockIdx.x] = lds[255];
}

__global__ void scan_s2(int* __restrict__ totals, int nb) {
    __shared__ int lds[256];
    int t = threadIdx.x;
    int v = (t < nb) ? totals[t] : 0;
    lds[t] = v;
    __syncthreads();
    #pragma unroll
    for (int off = 1; off < 256; off <<= 1) {
        int add = (t >= off) ? lds[t - off] : 0;
        __syncthreads();
        lds[t] += add;
        __syncthreads();
    }
    if (t < nb) totals[t] = lds[t] - v;   // exclusive over block totals
}

__global__ void scan_s3(int* __restrict__ row_ptr, const int* __restrict__ totals,
                        int* __restrict__ cursor, int N, int E) {
    int i = blockIdx.x * 256 + threadIdx.x;
    if (i < N) {
        int v = row_ptr[i] + totals[blockIdx.x];
        row_ptr[i] = v;
        cursor[i] = v;
    }
    if (i == 0) row_ptr[N] = E;
}

__global__ void scatter_kernel(const int* __restrict__ src, const int* __restrict__ dst,
                               int* __restrict__ cursor, int* __restrict__ col_src,
                               int* __restrict__ col_dst, int* __restrict__ col_eid, int E) {
    int e = blockIdx.x * 256 + threadIdx.x;
    if (e < E) {
        int d = dst[e];
        int pos = atomicAdd(&cursor[d], 1);
        col_src[pos] = src[e];
        col_dst[pos] = d;
        col_eid[pos] = e;
    }
}

// ---------------------------------------------------------------------------
// Pack We (fp32 [32,256]) into MFMA A-fragment order, bf16 hi + lo parts.
// WeP layout: [layer][part][tile][lane][8] shorts; layer stride 16384,
// lo part at +8192. A[m=lane&15][k=(lane>>4)*8+j].
// ---------------------------------------------------------------------------
__global__ void pack_we(const float* __restrict__ We0, const float* __restrict__ We1,
                        unsigned short* __restrict__ WeP) {
    int t = blockIdx.x * 256 + threadIdx.x;
    if (t >= 4096) return;
    int layer = t >> 11;
    int part  = (t >> 10) & 1;
    int tile  = (t >> 6) & 15;
    int lane  = t & 63;
    const float* We = layer ? We1 : We0;
    int ch = tile * 16 + (lane & 15);
    int kb = (lane >> 4) * 8;
    union { unsigned short u[8]; uint4 v; } out;
    #pragma unroll
    for (int j = 0; j < 8; ++j) {
        float w = We[(size_t)(kb + j) * 256 + ch];
        unsigned short hi = bf16hi(w);
        out.u[j] = part ? bf16hi(w - bf16tof(hi)) : hi;
    }
    *(uint4*)(WeP + (size_t)t * 8) = out.v;
}

// ---------------------------------------------------------------------------
// Pack W = [Wl | Wr] (fp32 [K,256] each) into MFMA B-frag order, hi+lo bf16.
// ---------------------------------------------------------------------------
__global__ void pack_w(const float* __restrict__ Wl, const float* __restrict__ Wr,
                       int KT, unsigned short* __restrict__ out) {
    int t = blockIdx.x * 256 + threadIdx.x;
    int per = KT * 2048;             // KT*32*64
    if (t >= 2 * per) return;
    int part = t / per;
    int rem  = t % per;
    int kt   = rem >> 11;
    int nt   = (rem >> 6) & 31;
    int lane = rem & 63;
    int n  = nt * 16 + (lane & 15);
    int kb = kt * 32 + ((lane >> 4) * 8);
    const float* W = (n < 256) ? (Wl + n) : (Wr + (n - 256));
    union { unsigned short u[8]; uint4 v; } o;
    #pragma unroll
    for (int j = 0; j < 8; ++j) {
        float w = W[(size_t)(kb + j) * 256];
        unsigned short hi = bf16hi(w);
        o.u[j] = part ? bf16hi(w - bf16tof(hi)) : hi;
    }
    *(uint4*)(out + (size_t)t * 8) = o.v;
}

// ---------------------------------------------------------------------------
// Split-bf16 MFMA GEMM: C[M,512] = A[M,K] @ [Wl|Wr] + [bl|br] (unchanged).
// ---------------------------------------------------------------------------
__global__ __launch_bounds__(256) void gemm_split(
    const float* __restrict__ A, int M, int K,
    const unsigned short* __restrict__ Bf,   // [2][KT][32][64][8]
    const float* __restrict__ bl, const float* __restrict__ br,
    float* __restrict__ C)
{
    __shared__ unsigned short Af[2][8][64][8];   // 16 KB
    const int tid  = threadIdx.x;
    const int lane = tid & 63;
    const int w    = tid >> 6;
    const int m0   = blockIdx.x * 128;
    const int n0   = blockIdx.y * 128;
    const int KT   = K >> 5;
    const int ntg0 = n0 >> 4;

    f32x4 acc[2][8];
    #pragma unroll
    for (int i = 0; i < 2; ++i)
        #pragma unroll
        for (int j = 0; j < 8; ++j) acc[i][j] = (f32x4){0.f, 0.f, 0.f, 0.f};

    const size_t partStride = (size_t)KT * 32 * 512;   // shorts

    for (int kt = 0; kt < KT; ++kt) {
        #pragma unroll
        for (int i = 0; i < 4; ++i) {
            int idx = tid * 4 + i;          // 0..1023 float4s
            int r   = idx >> 3;
            int kl  = (idx & 7) * 4;
            int gm  = m0 + r;
            float4 v = make_float4(0.f, 0.f, 0.f, 0.f);
            if (gm < M) v = *(const float4*)(A + (size_t)gm * K + kt * 32 + kl);
            unsigned short h0 = bf16hi(v.x), h1 = bf16hi(v.y);
            unsigned short h2 = bf16hi(v.z), h3 = bf16hi(v.w);
            unsigned short l0 = bf16hi(v.x - bf16tof(h0));
            unsigned short l1 = bf16hi(v.y - bf16tof(h1));
            unsigned short l2 = bf16hi(v.z - bf16tof(h2));
            unsigned short l3 = bf16hi(v.w - bf16tof(h3));
            int mt = r >> 4;
            int la = (r & 15) | ((kl >> 3) << 4);
            int j0 = kl & 7;
            *(uint2*)&Af[0][mt][la][j0] =
                make_uint2((unsigned int)h0 | ((unsigned int)h1 << 16),
                           (unsigned int)h2 | ((unsigned int)h3 << 16));
            *(uint2*)&Af[1][mt][la][j0] =
                make_uint2((unsigned int)l0 | ((unsigned int)l1 << 16),
                           (unsigned int)l2 | ((unsigned int)l3 << 16));
        }
        __syncthreads();

        bf16x8 ah0 = *(const bf16x8*)&Af[0][w * 2 + 0][lane][0];
        bf16x8 ah1 = *(const bf16x8*)&Af[0][w * 2 + 1][lane][0];
        bf16x8 al0 = *(const bf16x8*)&Af[1][w * 2 + 0][lane][0];
        bf16x8 al1 = *(const bf16x8*)&Af[1][w * 2 + 1][lane][0];

        const unsigned short* bbase =
            Bf + ((size_t)kt * 32 + ntg0) * 512 + (size_t)lane * 8;
        #pragma unroll
        for (int nt = 0; nt < 8; ++nt) {
            bf16x8 bh  = *(const bf16x8*)(bbase + (size_t)nt * 512);
            bf16x8 blv = *(const bf16x8*)(bbase + partStride + (size_t)nt * 512);
            acc[0][nt] = __builtin_amdgcn_mfma_f32_16x16x32_bf16(ah0, bh,  acc[0][nt], 0, 0, 0);
            acc[1][nt] = __builtin_amdgcn_mfma_f32_16x16x32_bf16(ah1, bh,  acc[1][nt], 0, 0, 0);
            acc[0][nt] = __builtin_amdgcn_mfma_f32_16x16x32_bf16(ah0, blv, acc[0][nt], 0, 0, 0);
            acc[1][nt] = __builtin_amdgcn_mfma_f32_16x16x32_bf16(ah1, blv, acc[1][nt], 0, 0, 0);
            acc[0][nt] = __builtin_amdgcn_mfma_f32_16x16x32_bf16(al0, bh,  acc[0][nt], 0, 0, 0);
            acc[1][nt] = __builtin_amdgcn_mfma_f32_16x16x32_bf16(al1, bh,  acc[1][nt], 0, 0, 0);
        }
        __syncthreads();
    }

    const int q  = lane >> 4;
    const int cl = lane & 15;
    #pragma unroll
    for (int mti = 0; mti < 2; ++mti) {
        int gmb = m0 + (w * 2 + mti) * 16 + q * 4;
        #pragma unroll
        for (int nt = 0; nt < 8; ++nt) {
            int col = n0 + nt * 16 + cl;
            float bia = (col < 256) ? bl[col] : br[col - 256];
            #pragma unroll
            for (int r = 0; r < 4; ++r) {
                int gm = gmb + r;
                if (gm < M) C[(size_t)gm * 512 + col] = acc[mti][nt][r] + bia;
            }
        }
    }
}

// ---------------------------------------------------------------------------
// FUSED logit + aggregate, edge-aligned. Wave owns a CONTIGUOUS CSR range of
// W edges (7 chunks x 16). Per chunk: phase A = proven MFMA logit pipeline
// (all lanes end with full lph via xor-reduce); phase B = per-lane (4ch) scan
// over the 16 edges, xl rows L1-hot (just read by this wave), p broadcast via
// ds_bpermute. dst runs fully inside the range -> finalize + direct write (no
// atomics). Runs touching a range boundary (~2/wave) -> atomicAdd raw sums
// into nmr(bufB) + denomB; fixed by finalize kernel. Predicate from row_ptr
// is computed identically on both sides. No-max softmax (validated r3-r6).
// No occupancy attributes (r1-r3: any forced VGPR cap spills 1:1).
// ---------------------------------------------------------------------------
template<bool PROJ>
__global__ __launch_bounds__(256) void gat_fused_t(
    const float* __restrict__ xlxr,       // [N,512]
    const float* __restrict__ edge_attr,  // [E,32]
    const int* __restrict__ col_src,      // [E] CSR order
    const int* __restrict__ col_dst,      // [E] CSR order
    const int* __restrict__ col_eid,      // [E] CSR order
    const int* __restrict__ row_ptr,      // [N+1]
    const unsigned short* __restrict__ WePl, // hi @0, lo @+8192 shorts
    const float* __restrict__ att,        // [256]
    const float* __restrict__ bias,       // [256]
    float* __restrict__ nmr,              // bufB: direct hout + atomic numer
    const float* __restrict__ Wout,       // [256]  (PROJ)
    const float* __restrict__ bout,       // [1]    (PROJ)
    float* __restrict__ out,              // [N,1]  (PROJ)
    float* __restrict__ denomB,           // [N,4] zeroed
    int E, int W)
{
    __shared__ unsigned short AhiS[16][64][8];   // 16 KB
    __shared__ unsigned short AloS[16][64][8];   // 16 KB
    const int tid = threadIdx.x;
    #pragma unroll
    for (int i = 0; i < 4; ++i) {
        int idx = tid * 4 + i;                   // 1024 uint4s each
        ((uint4*)&AhiS[0][0][0])[idx] = ((const uint4*)WePl)[idx];
        ((uint4*)&AloS[0][0][0])[idx] = ((const uint4*)(WePl + 8192))[idx];
    }
    __syncthreads();

    const int lane  = tid & 63;
    const int wid   = tid >> 6;
    const int q     = lane >> 4;
    const int e_sub = lane & 15;
    const int kb    = q * 8;
    const int ch4   = lane * 4;      // phase-B owned channels

    const int gw = blockIdx.x * 4 + wid;
    const int s_range = gw * W;
    if (s_range >= E) return;        // after __syncthreads: safe
    const int eEnd = min(E, s_range + W);

    const float4 bia4 = *(const float4*)(bias + ch4);
    float4 wo4 = make_float4(0.f, 0.f, 0.f, 0.f);
    if (PROJ) wo4 = *(const float4*)(Wout + ch4);

    int curDst = -1;
    float4 accB = make_float4(0.f, 0.f, 0.f, 0.f);
    float denB = 0.f;

    auto flush = [&]() {
        if (curDst >= 0) {
            int ra = row_ptr[curDst], rb = row_ptr[curDst + 1];
            bool comp = (ra % W != 0) && (rb % W != 0) && (ra / W == (rb - 1) / W);
            if (comp) {
                float inv = 1.0f / denB;
                float4 o;
                o.x = fmaxf(fmaf(accB.x, inv, bia4.x), 0.f);
                o.y = fmaxf(fmaf(accB.y, inv, bia4.y), 0.f);
                o.z = fmaxf(fmaf(accB.z, inv, bia4.z), 0.f);
                o.w = fmaxf(fmaf(accB.w, inv, bia4.w), 0.f);
                if (!PROJ) {
                    *(float4*)(nmr + (size_t)curDst * 256 + ch4) = o;
                } else {
                    float s = o.x * wo4.x;
                    s = fmaf(o.y, wo4.y, s);
                    s = fmaf(o.z, wo4.z, s);
                    s = fmaf(o.w, wo4.w, s);
                    #pragma unroll
                    for (int off = 32; off > 0; off >>= 1)
                        s += __shfl_xor(s, off, 64);
                    if (lane == 0) out[curDst] = s + bout[0];
                }
            } else {
                float* np = nmr + (size_t)curDst * 256 + ch4;
                atomicAdd(np + 0, accB.x);
                atomicAdd(np + 1, accB.y);
                atomicAdd(np + 2, accB.z);
                atomicAdd(np + 3, accB.w);
                if (e_sub == 0) atomicAdd(denomB + curDst * 4 + q, denB);
            }
            accB = make_float4(0.f, 0.f, 0.f, 0.f);
            denB = 0.f;
        }
    };

    for (int base = s_range; base < eEnd; base += 16) {
        const int cnt  = min(16, eEnd - base);
        const int slot = base + e_sub;
        const int sc   = min(slot, eEnd - 1);
        const int eid  = col_eid[sc];
        const int srcn = col_src[sc];
        const int dstn = col_dst[sc];

        // ================= Phase A: logits =================
        const float* ap = edge_attr + (size_t)eid * 32 + kb;
        float4 v0 = *(const float4*)ap;
        float4 v1 = *(const float4*)(ap + 4);
        float vv[8] = {v0.x, v0.y, v0.z, v0.w, v1.x, v1.y, v1.z, v1.w};
        union { bf16x8 v; unsigned short u[8]; } bh, bl;
        #pragma unroll
        for (int i = 0; i < 8; ++i) {
            unsigned short hh = bf16hi(vv[i]);
            bh.u[i] = hh;
            bl.u[i] = bf16hi(vv[i] - bf16tof(hh));
        }

        const float* xlp = xlxr + (size_t)srcn * 512 + q * 4;
        const float* xrp = xlxr + (size_t)dstn * 512 + 256 + q * 4;

        float lph[4] = {0.f, 0.f, 0.f, 0.f};
        #pragma unroll
        for (int t = 0; t < 16; ++t) {
            bf16x8 ahi = *(const bf16x8*)&AhiS[t][lane][0];
            bf16x8 alo = *(const bf16x8*)&AloS[t][lane][0];
            f32x4 macc = {0.f, 0.f, 0.f, 0.f};
            macc = __builtin_amdgcn_mfma_f32_16x16x32_bf16(ahi, bh.v, macc, 0, 0, 0);
            macc = __builtin_amdgcn_mfma_f32_16x16x32_bf16(ahi, bl.v, macc, 0, 0, 0);
            macc = __builtin_amdgcn_mfma_f32_16x16x32_bf16(alo, bh.v, macc, 0, 0, 0);
            const float4 xl4 = *(const float4*)(xlp + t * 16);
            const float4 xr4 = *(const float4*)(xrp + t * 16);
            const float4 at4 = *(const float4*)(att + t * 16 + q * 4);
            float z0 = macc[0] + xl4.x + xr4.x; z0 = (z0 > 0.f) ? z0 : NEG_SLOPE * z0;
            float z1 = macc[1] + xl4.y + xr4.y; z1 = (z1 > 0.f) ? z1 : NEG_SLOPE * z1;
            float z2 = macc[2] + xl4.z + xr4.z; z2 = (z2 > 0.f) ? z2 : NEG_SLOPE * z2;
            float z3 = macc[3] + xl4.w + xr4.w; z3 = (z3 > 0.f) ? z3 : NEG_SLOPE * z3;
            float s = z0 * at4.x;
            s = fmaf(z1, at4.y, s);
            s = fmaf(z2, at4.z, s);
            s = fmaf(z3, at4.w, s);
            lph[t >> 2] += s;
        }
        #pragma unroll
        for (int hh = 0; hh < 4; ++hh) {
            lph[hh] += __shfl_xor(lph[hh], 16, 64);
            lph[hh] += __shfl_xor(lph[hh], 32, 64);
        }
        // every lane now has the full logit for its edge e_sub; select own head
        float lsel = (q == 0) ? lph[0] : (q == 1) ? lph[1] : (q == 2) ? lph[2] : lph[3];
        float psrc = __expf(lsel);   // p[e_sub][q] on lane (q,e_sub)

        // ================= Phase B: segmented accumulate (xl L1-hot) =======
        auto phaseB = [&](int cnt2) {
            for (int eb = 0; eb < cnt2; eb += 4) {
                float pv[4]; int sv[4], dv[4];
                #pragma unroll
                for (int i = 0; i < 4; ++i) {
                    int e = eb + i;
                    int ec = (e < cnt2) ? e : cnt2 - 1;
                    pv[i] = __shfl(psrc, (lane & 48) | ec, 64);
                    if (e >= cnt2) pv[i] = 0.f;
                    sv[i] = __shfl(srcn, ec, 64);
                    dv[i] = __shfl(dstn, ec, 64);
                }
                float4 xv[4];
                #pragma unroll
                for (int i = 0; i < 4; ++i)
                    xv[i] = *(const float4*)(xlxr + (size_t)sv[i] * 512 + ch4);
                #pragma unroll
                for (int i = 0; i < 4; ++i) {
                    if (dv[i] != curDst) { flush(); curDst = dv[i]; }
                    denB += pv[i];
                    accB.x = fmaf(pv[i], xv[i].x, accB.x);
                    accB.y = fmaf(pv[i], xv[i].y, accB.y);
                    accB.z = fmaf(pv[i], xv[i].z, accB.z);
                    accB.w = fmaf(pv[i], xv[i].w, accB.w);
                }
            }
        };
        if (cnt == 16) phaseB(16); else phaseB(cnt);
    }
    flush();   // tail run
}

// ---------------------------------------------------------------------------
// Finalize: fix boundary-run nodes (atomic-accumulated) and deg-0 nodes.
// Complete nodes were direct-written by the fused kernel -> skip.
// ---------------------------------------------------------------------------
template<bool PROJ>
__global__ __launch_bounds__(256) void finalize_t(
    const int* __restrict__ row_ptr,
    const float* __restrict__ denomB,    // [N,4]
    const float* __restrict__ bias,      // [256]
    float* __restrict__ nmr,             // bufB raw sums (in-place for !PROJ)
    const float* __restrict__ Wout, const float* __restrict__ bout,
    float* __restrict__ out, int N, int W)
{
    const int tid  = threadIdx.x;
    const int lane = tid & 63;
    const int wid  = tid >> 6;
    const int n = blockIdx.x * 4 + wid;
    if (n >= N) return;
    const int q   = lane >> 4;
    const int ch4 = lane * 4;

    const int a = row_ptr[n], b = row_ptr[n + 1];
    float4 o;
    if (a == b) {
        const float4 bia = *(const float4*)(bias + ch4);
        o.x = fmaxf(bia.x, 0.f);
        o.y = fmaxf(bia.y, 0.f);
        o.z = fmaxf(bia.z, 0.f);
        o.w = fmaxf(bia.w, 0.f);
    } else {
        bool comp = (a % W != 0) && (b % W != 0) && (a / W == (b - 1) / W);
        if (comp) return;   // already direct-written
        const float4 nm = *(const float4*)(nmr + (size_t)n * 256 + ch4);
        const float inv = 1.0f / denomB[n * 4 + q];
        const float4 bia = *(const float4*)(bias + ch4);
        o.x = fmaxf(fmaf(nm.x, inv, bia.x), 0.f);
        o.y = fmaxf(fmaf(nm.y, inv, bia.y), 0.f);
        o.z = fmaxf(fmaf(nm.z, inv, bia.z), 0.f);
        o.w = fmaxf(fmaf(nm.w, inv, bia.w), 0.f);
    }
    if (!PROJ) {
        *(float4*)(nmr + (size_t)n * 256 + ch4) = o;
    } else {
        const float4 w4 = *(const float4*)(Wout + ch4);
        float s = o.x * w4.x;
        s = fmaf(o.y, w4.y, s);
        s = fmaf(o.z, w4.z, s);
        s = fmaf(o.w, w4.w, s);
        #pragma unroll
        for (int off = 32; off > 0; off >>= 1)
            s += __shfl_xor(s, off, 64);
        if (lane == 0) out[n] = s + bout[0];
    }
}

// ---------------------------------------------------------------------------
extern "C" void kernel_launch(void* const* d_in, const int* in_sizes, int n_in,
                              void* d_out, int out_size, void* d_ws, size_t ws_size,
                              hipStream_t stream) {
    const float* x         = (const float*)d_in[0];
    const int*   edge_idx  = (const int*)d_in[1];
    const float* edge_attr = (const float*)d_in[2];
    const float* W_l0 = (const float*)d_in[3];
    const float* b_l0 = (const float*)d_in[4];
    const float* W_r0 = (const float*)d_in[5];
    const float* b_r0 = (const float*)d_in[6];
    const float* W_e0 = (const float*)d_in[7];
    const float* att0 = (const float*)d_in[8];
    const float* bias0= (const float*)d_in[9];
    const float* W_l1 = (const float*)d_in[10];
    const float* b_l1 = (const float*)d_in[11];
    const float* W_r1 = (const float*)d_in[12];
    const float* b_r1 = (const float*)d_in[13];
    const float* W_e1 = (const float*)d_in[14];
    const float* att1 = (const float*)d_in[15];
    const float* bias1= (const float*)d_in[16];
    const float* W_out= (const float*)d_in[17];
    const float* b_out= (const float*)d_in[18];

    const int N = in_sizes[0] / 512;      // 50000
    const int E = in_sizes[1] / 2;        // 800000

    const int* src = edge_idx;
    const int* dst = edge_idx + E;

    // workspace layout (~168 MB)
    char* ws = (char*)d_ws;
    size_t off = 0;
    float* bufA   = (float*)(ws + off); off += (size_t)N * 512 * 4;   // 102.4 MB
    float* bufB   = (float*)(ws + off); off += (size_t)N * 256 * 4;   //  51.2 MB
    float* denomB = (float*)(ws + off); off += (size_t)N * 4 * 4;     //   0.8 MB
    int* row_ptr  = (int*)(ws + off);   off += (((size_t)(N + 1) * 4 + 255) & ~(size_t)255);
    int* cursor   = (int*)(ws + off);   off += (((size_t)N * 4 + 255) & ~(size_t)255);
    int* col_src  = (int*)(ws + off);   off += (size_t)E * 4;
    int* col_dst  = (int*)(ws + off);   off += (size_t)E * 4;
    int* col_eid  = (int*)(ws + off);   off += (size_t)E * 4;
    int* totals   = (int*)(ws + off);   off += 1024;
    unsigned short* WeP = (unsigned short*)(ws + off); off += 4096 * 8 * 2;        // 64 KB
    unsigned short* Bf0 = (unsigned short*)(ws + off); off += (size_t)2 * 16 * 32 * 64 * 8 * 2; // 1 MB
    unsigned short* Bf1 = (unsigned short*)(ws + off); off += (size_t)2 * 8 * 32 * 64 * 8 * 2;  // 512 KB

    const int nbE = (E + 255) / 256;
    const int nbN = (N + 255) / 256;

    // ---- CSR build + weight prepack ----
    hipMemsetAsync(cursor, 0, (size_t)N * 4, stream);
    hist_kernel<<<nbE, 256, 0, stream>>>(dst, cursor, E);
    scan_s1<<<nbN, 256, 0, stream>>>(cursor, row_ptr, totals, N);
    scan_s2<<<1, 256, 0, stream>>>(totals, nbN);
    scan_s3<<<nbN, 256, 0, stream>>>(row_ptr, totals, cursor, N, E);
    scatter_kernel<<<nbE, 256, 0, stream>>>(src, dst, cursor, col_src, col_dst, col_eid, E);
    pack_we<<<16, 256, 0, stream>>>(W_e0, W_e1, WeP);
    pack_w<<<256, 256, 0, stream>>>(W_l0, W_r0, 16, Bf0);
    pack_w<<<128, 256, 0, stream>>>(W_l1, W_r1, 8, Bf1);

    dim3 ggrid((N + 127) / 128, 4);

    // fused-kernel geometry: 8192 waves, contiguous edge ranges
    const int NW  = 8192;
    const int nch = (E + 15) / 16;
    const int C   = (nch + NW - 1) / NW;   // chunks per wave
    const int W   = C * 16;                // edges per wave range (112)
    const int nfin = (N + 3) / 4;

    // ---- Layer 0 ----
    gemm_split<<<ggrid, 256, 0, stream>>>(x, N, 512, Bf0, b_l0, b_r0, bufA);
    hipMemsetAsync(bufB,   0, (size_t)N * 256 * 4, stream);
    hipMemsetAsync(denomB, 0, (size_t)N * 4 * 4,   stream);
    gat_fused_t<false><<<2048, 256, 0, stream>>>(
        bufA, edge_attr, col_src, col_dst, col_eid, row_ptr, WeP, att0, bias0,
        bufB, nullptr, nullptr, nullptr, denomB, E, W);
    finalize_t<false><<<nfin, 256, 0, stream>>>(
        row_ptr, denomB, bias0, bufB, nullptr, nullptr, nullptr, N, W);

    // ---- Layer 1 ----
    gemm_split<<<ggrid, 256, 0, stream>>>(bufB, N, 256, Bf1, b_l1, b_r1, bufA);
    hipMemsetAsync(bufB,   0, (size_t)N * 256 * 4, stream);
    hipMemsetAsync(denomB, 0, (size_t)N * 4 * 4,   stream);
    gat_fused_t<true><<<2048, 256, 0, stream>>>(
        bufA, edge_attr, col_src, col_dst, col_eid, row_ptr, WeP + 16384, att1, bias1,
        bufB, W_out, b_out, (float*)d_out, denomB, E, W);
    finalize_t<true><<<nfin, 256, 0, stream>>>(
        row_ptr, denomB, bias1, bufB, W_out, b_out, (float*)d_out, N, W);
}